// Round 3
// baseline (733.310 us; speedup 1.0000x reference)
//
#include <hip/hip_runtime.h>
#include <cstdint>
#include <cstddef>

#define INF  4096
#define OUTF 4096
#define NTOK 8192
#define TOPK 128

// bf16 staging buffers (bit patterns as ushort). Fully rewritten every call.
__device__ unsigned short g_xb[(size_t)NTOK * INF];  // x in bf16, [t][i], 64 MB
__device__ unsigned short g_wb[(size_t)OUTF * INF];  // masked W in bf16, [o][i], 32 MB

__device__ __forceinline__ unsigned short f2bf(float f) {
  unsigned u = __float_as_uint(f);
  return (unsigned short)((u + 0x7FFFu + ((u >> 16) & 1u)) >> 16);  // RNE
}

__device__ __forceinline__ void gload_lds16(const void* g, void* l) {
  __builtin_amdgcn_global_load_lds(
      (const __attribute__((address_space(1))) void*)g,
      (__attribute__((address_space(3))) void*)l, 16, 0, 0);
}

// ---------------------------------------------------------------------------
// x f32 -> bf16 (vectorized: 32 B in / 16 B out per iter)
// ---------------------------------------------------------------------------
__global__ __launch_bounds__(256) void xcvt(const float* __restrict__ x) {
  const size_t nOct = (size_t)NTOK * INF / 8;
  size_t gid = (size_t)blockIdx.x * 256 + threadIdx.x;
  for (size_t t = gid; t < nOct; t += (size_t)2048 * 256) {
    const float4* p = reinterpret_cast<const float4*>(x + t * 8);
    float4 a = p[0], b = p[1];
    uint4 pk;
    pk.x = f2bf(a.x) | ((unsigned)f2bf(a.y) << 16);
    pk.y = f2bf(a.z) | ((unsigned)f2bf(a.w) << 16);
    pk.z = f2bf(b.x) | ((unsigned)f2bf(b.y) << 16);
    pk.w = f2bf(b.z) | ((unsigned)f2bf(b.w) << 16);
    *reinterpret_cast<uint4*>(&g_xb[t * 8]) = pk;
  }
}

// ---------------------------------------------------------------------------
// Per-row exact top-128 of |w| (tie-break: |w| desc, idx asc = jax.lax.top_k),
// emitting the dense masked bf16 row. Parallel suffix scan replaces R1's
// serial tid==0 loops (R1: ~173 us; this: ~20 us predicted).
// ---------------------------------------------------------------------------
__global__ __launch_bounds__(256) void topk_wb(const float* __restrict__ W) {
  const int o = blockIdx.x, tid = threadIdx.x;
  __shared__ unsigned bins[2048];
  __shared__ unsigned sfx[256];
  __shared__ unsigned sB, sNeed, sNc, nChosen;
  __shared__ unsigned cval[256];
  __shared__ unsigned short cidx[256];
  __shared__ unsigned short chosen[TOPK];

  float wv[16];
  const float* row = W + (size_t)o * INF;
  #pragma unroll
  for (int j = 0; j < 4; ++j) {
    float4 v = *reinterpret_cast<const float4*>(row + tid * 16 + j * 4);
    wv[j*4+0] = v.x; wv[j*4+1] = v.y; wv[j*4+2] = v.z; wv[j*4+3] = v.w;
  }
  #pragma unroll
  for (int j = 0; j < 8; ++j) bins[tid + j * 256] = 0;
  if (tid == 0) sNc = 0;
  __syncthreads();

  // |w|*2^17 is a pure exponent shift (exact) -> strictly monotone binning.
  int bj[16];
  #pragma unroll
  for (int j = 0; j < 16; ++j) {
    int b = (int)(fabsf(wv[j]) * 131072.0f);
    bj[j] = b > 2047 ? 2047 : b;
    atomicAdd(&bins[bj[j]], 1u);
  }
  __syncthreads();

  unsigned cs = 0;
  #pragma unroll
  for (int j = 0; j < 8; ++j) cs += bins[tid * 8 + j];
  sfx[tid] = cs;
  __syncthreads();
  // Hillis-Steele suffix scan over 256 chunk sums (8 rounds).
  for (int d = 1; d < 256; d <<= 1) {
    unsigned v = sfx[tid] + ((tid + d < 256) ? sfx[tid + d] : 0u);
    __syncthreads();
    sfx[tid] = v;
    __syncthreads();
  }
  // Exactly one thread owns the bracket chunk (sfx is non-increasing).
  {
    unsigned mine = sfx[tid];
    unsigned nxt = (tid < 255) ? sfx[tid + 1] : 0u;
    if (mine >= TOPK && nxt < TOPK) {
      unsigned acc = nxt;
      for (int j = 7; j >= 0; --j) {
        unsigned c = bins[tid * 8 + j];
        if (acc + c >= TOPK) { sB = (unsigned)(tid * 8 + j); sNeed = TOPK - acc; break; }
        acc += c;
      }
    }
  }
  __syncthreads();
  const int B = (int)sB;
  const unsigned need = sNeed;

  // Bracket-bin candidates (expected ~2 per row for uniform weights).
  #pragma unroll
  for (int j = 0; j < 16; ++j) {
    if (bj[j] == B) {
      unsigned p = atomicAdd(&sNc, 1u);
      if (p < 256u) { cval[p] = __float_as_uint(fabsf(wv[j])); cidx[p] = (unsigned short)(tid*16+j); }
    }
  }
  __syncthreads();
  if (tid == 0) {  // tiny exact sort by (|w| desc, idx asc)
    int n = sNc < 256u ? (int)sNc : 256;
    for (int a = 1; a < n; ++a) {
      unsigned v = cval[a]; unsigned short id = cidx[a]; int p = a - 1;
      while (p >= 0 && (cval[p] < v || (cval[p] == v && cidx[p] > id))) {
        cval[p+1] = cval[p]; cidx[p+1] = cidx[p]; --p;
      }
      cval[p+1] = v; cidx[p+1] = id;
    }
    int m = (int)need < n ? (int)need : n;
    for (int j = 0; j < m; ++j) chosen[j] = cidx[j];
    nChosen = (unsigned)m;
  }
  __syncthreads();
  const unsigned nCh = nChosen;

  unsigned short out[16];
  #pragma unroll
  for (int j = 0; j < 16; ++j) {
    bool sel = bj[j] > B;
    if (bj[j] == B) {
      unsigned short idx = (unsigned short)(tid * 16 + j);
      for (unsigned q = 0; q < nCh; ++q) if (chosen[q] == idx) { sel = true; break; }
    }
    out[j] = sel ? f2bf(wv[j]) : (unsigned short)0;
  }
  uint4 pk0, pk1;
  pk0.x = out[0] | ((unsigned)out[1]  << 16); pk0.y = out[2]  | ((unsigned)out[3]  << 16);
  pk0.z = out[4] | ((unsigned)out[5]  << 16); pk0.w = out[6]  | ((unsigned)out[7]  << 16);
  pk1.x = out[8] | ((unsigned)out[9]  << 16); pk1.y = out[10] | ((unsigned)out[11] << 16);
  pk1.z = out[12]| ((unsigned)out[13] << 16); pk1.w = out[14] | ((unsigned)out[15] << 16);
  uint4* dst = reinterpret_cast<uint4*>(&g_wb[(size_t)o * INF + tid * 16]);
  dst[0] = pk0; dst[1] = pk1;
}

// ---------------------------------------------------------------------------
// m97-structure bf16 GEMM: y[t,o] = sum_k xb[t,k]*wb[o,k] + bias[o].
// 128x128 tile, BK=32, 256 threads (2x2 waves, 64x64 each), single-buffered
// LDS with global_load_lds width-16 staging, 16 MFMA(16x16x32)/wave/K-step.
// Linear LDS layout: at 64 B row stride the b128 frag reads are slot-balanced
// across the wave (8 lanes per 16B bank-slot), so no swizzle is required.
// ---------------------------------------------------------------------------
typedef __attribute__((ext_vector_type(8))) short bf16x8;
typedef __attribute__((ext_vector_type(4))) float f32x4;

#define BM 128
#define BN 128
#define BK 32

__global__ __launch_bounds__(256) void gemm_bt(const float* __restrict__ bias,
                                               float* __restrict__ y) {
  __shared__ short As[BM * BK];   // [128][32] bf16, 8 KB
  __shared__ short Bs[BN * BK];

  const int tid = threadIdx.x;
  const int wid = tid >> 6, ln = tid & 63;

  // XCD-aware swizzle (nwg = 2048, 2048 % 8 == 0 -> simple form bijective).
  const int bid = (int)blockIdx.x;
  const int swz = (bid & 7) * 256 + (bid >> 3);
  const int bn = swz & 31, bm = swz >> 5;
  const int m0 = bm * BM, n0 = bn * BN;

  const int wm = (wid >> 1) * 64, wn = (wid & 1) * 64;

  f32x4 acc[4][4] = {};

  // Staging map: issue covers 4096 B (4 waves x 64 lanes x 16 B); row = L/64.
  const int arow1 = (wid << 4) + (ln >> 2);      // 0..63
  const int arow2 = arow1 + 64;                  // 64..127
  const int acol  = (ln & 3) * 8;                // element offset in K
  char* ldsA1 = (char*)As + wid * 1024;          // wave-uniform LDS dests
  char* ldsA2 = (char*)As + 4096 + wid * 1024;
  char* ldsB1 = (char*)Bs + wid * 1024;
  char* ldsB2 = (char*)Bs + 4096 + wid * 1024;

  const int fr = ln & 15, kh = (ln >> 4) * 16;   // frag row / K-halfword byte

  for (int k0 = 0; k0 < INF; k0 += BK) {
    __syncthreads();   // previous compute done before overwrite
    gload_lds16(g_xb + (size_t)(m0 + arow1) * INF + k0 + acol, ldsA1);
    gload_lds16(g_xb + (size_t)(m0 + arow2) * INF + k0 + acol, ldsA2);
    gload_lds16(g_wb + (size_t)(n0 + arow1) * INF + k0 + acol, ldsB1);
    gload_lds16(g_wb + (size_t)(n0 + arow2) * INF + k0 + acol, ldsB2);
    __syncthreads();   // barrier drains vmcnt -> tile visible

    bf16x8 aF[4], bF[4];
    #pragma unroll
    for (int m = 0; m < 4; ++m)
      aF[m] = *reinterpret_cast<const bf16x8*>((char*)As + (wm + m * 16 + fr) * 64 + kh);
    #pragma unroll
    for (int n = 0; n < 4; ++n)
      bF[n] = *reinterpret_cast<const bf16x8*>((char*)Bs + (wn + n * 16 + fr) * 64 + kh);
    #pragma unroll
    for (int m = 0; m < 4; ++m)
      #pragma unroll
      for (int n = 0; n < 4; ++n)
        acc[m][n] = __builtin_amdgcn_mfma_f32_16x16x32_bf16(aF[m], bF[n], acc[m][n], 0, 0, 0);
  }

  // Epilogue: C/D layout col = lane&15, row = (lane>>4)*4 + reg (m89-verified).
  const int fq = ln >> 4;
  #pragma unroll
  for (int n = 0; n < 4; ++n) {
    const int col = n0 + wn + n * 16 + fr;
    const float bb = bias[col];
    #pragma unroll
    for (int m = 0; m < 4; ++m) {
      const int rbase = m0 + wm + m * 16 + fq * 4;
      #pragma unroll
      for (int q = 0; q < 4; ++q)
        y[(size_t)(rbase + q) * OUTF + col] = acc[m][n][q] + bb;
    }
  }
}

extern "C" void kernel_launch(void* const* d_in, const int* in_sizes, int n_in,
                              void* d_out, int out_size, void* d_ws, size_t ws_size,
                              hipStream_t stream) {
  const float* x      = (const float*)d_in[0];
  const float* weight = (const float*)d_in[1];
  const float* bias   = (const float*)d_in[2];
  float*       y      = (float*)d_out;

  hipLaunchKernelGGL(xcvt,    dim3(2048), dim3(256), 0, stream, x);
  hipLaunchKernelGGL(topk_wb, dim3(OUTF), dim3(256), 0, stream, weight);
  hipLaunchKernelGGL(gemm_bt, dim3((NTOK / BM) * (OUTF / BN)), dim3(256), 0, stream,
                     bias, y);
}

// Round 6
// 520.456 us; speedup vs baseline: 1.4090x; 1.4090x over previous
//
#include <hip/hip_runtime.h>
#include <cstdint>
#include <cstddef>

#define INF  4096
#define OUTF 4096
#define NTOK 8192
#define TOPK 128

// bf16 staging buffers (bit patterns as ushort). Fully rewritten every call.
__device__ unsigned short g_xb[(size_t)NTOK * INF];  // x in bf16, [t][i], 64 MB
__device__ unsigned short g_wb[(size_t)OUTF * INF];  // masked W in bf16, [o][i], 32 MB

__device__ __forceinline__ unsigned short f2bf(float f) {
  unsigned u = __float_as_uint(f);
  return (unsigned short)((u + 0x7FFFu + ((u >> 16) & 1u)) >> 16);  // RNE
}

__device__ __forceinline__ void gload_lds16(const void* g, void* l) {
  __builtin_amdgcn_global_load_lds(
      (const __attribute__((address_space(1))) void*)g,
      (__attribute__((address_space(3))) void*)l, 16, 0, 0);
}

// ---------------------------------------------------------------------------
// x f32 -> bf16 (vectorized: 32 B in / 16 B out per iter)  [unchanged, R3-good]
// ---------------------------------------------------------------------------
__global__ __launch_bounds__(256) void xcvt(const float* __restrict__ x) {
  const size_t nOct = (size_t)NTOK * INF / 8;
  size_t gid = (size_t)blockIdx.x * 256 + threadIdx.x;
  for (size_t t = gid; t < nOct; t += (size_t)2048 * 256) {
    const float4* p = reinterpret_cast<const float4*>(x + t * 8);
    float4 a = p[0], b = p[1];
    uint4 pk;
    pk.x = f2bf(a.x) | ((unsigned)f2bf(a.y) << 16);
    pk.y = f2bf(a.z) | ((unsigned)f2bf(a.w) << 16);
    pk.z = f2bf(b.x) | ((unsigned)f2bf(b.y) << 16);
    pk.w = f2bf(b.z) | ((unsigned)f2bf(b.w) << 16);
    *reinterpret_cast<uint4*>(&g_xb[t * 8]) = pk;
  }
}

// ---------------------------------------------------------------------------
// Per-row exact top-128 of |w| (tie-break matches jax.lax.top_k), emitting the
// dense masked bf16 row.  [unchanged, R3-good]
// ---------------------------------------------------------------------------
__global__ __launch_bounds__(256) void topk_wb(const float* __restrict__ W) {
  const int o = blockIdx.x, tid = threadIdx.x;
  __shared__ unsigned bins[2048];
  __shared__ unsigned sfx[256];
  __shared__ unsigned sB, sNeed, sNc, nChosen;
  __shared__ unsigned cval[256];
  __shared__ unsigned short cidx[256];
  __shared__ unsigned short chosen[TOPK];

  float wv[16];
  const float* row = W + (size_t)o * INF;
  #pragma unroll
  for (int j = 0; j < 4; ++j) {
    float4 v = *reinterpret_cast<const float4*>(row + tid * 16 + j * 4);
    wv[j*4+0] = v.x; wv[j*4+1] = v.y; wv[j*4+2] = v.z; wv[j*4+3] = v.w;
  }
  #pragma unroll
  for (int j = 0; j < 8; ++j) bins[tid + j * 256] = 0;
  if (tid == 0) sNc = 0;
  __syncthreads();

  int bj[16];
  #pragma unroll
  for (int j = 0; j < 16; ++j) {
    int b = (int)(fabsf(wv[j]) * 131072.0f);
    bj[j] = b > 2047 ? 2047 : b;
    atomicAdd(&bins[bj[j]], 1u);
  }
  __syncthreads();

  unsigned cs = 0;
  #pragma unroll
  for (int j = 0; j < 8; ++j) cs += bins[tid * 8 + j];
  sfx[tid] = cs;
  __syncthreads();
  for (int d = 1; d < 256; d <<= 1) {
    unsigned v = sfx[tid] + ((tid + d < 256) ? sfx[tid + d] : 0u);
    __syncthreads();
    sfx[tid] = v;
    __syncthreads();
  }
  {
    unsigned mine = sfx[tid];
    unsigned nxt = (tid < 255) ? sfx[tid + 1] : 0u;
    if (mine >= TOPK && nxt < TOPK) {
      unsigned acc = nxt;
      for (int j = 7; j >= 0; --j) {
        unsigned c = bins[tid * 8 + j];
        if (acc + c >= TOPK) { sB = (unsigned)(tid * 8 + j); sNeed = TOPK - acc; break; }
        acc += c;
      }
    }
  }
  __syncthreads();
  const int B = (int)sB;
  const unsigned need = sNeed;

  #pragma unroll
  for (int j = 0; j < 16; ++j) {
    if (bj[j] == B) {
      unsigned p = atomicAdd(&sNc, 1u);
      if (p < 256u) { cval[p] = __float_as_uint(fabsf(wv[j])); cidx[p] = (unsigned short)(tid*16+j); }
    }
  }
  __syncthreads();
  if (tid == 0) {
    int n = sNc < 256u ? (int)sNc : 256;
    for (int a = 1; a < n; ++a) {
      unsigned v = cval[a]; unsigned short id = cidx[a]; int p = a - 1;
      while (p >= 0 && (cval[p] < v || (cval[p] == v && cidx[p] > id))) {
        cval[p+1] = cval[p]; cidx[p+1] = cidx[p]; --p;
      }
      cval[p+1] = v; cidx[p+1] = id;
    }
    int m = (int)need < n ? (int)need : n;
    for (int j = 0; j < m; ++j) chosen[j] = cidx[j];
    nChosen = (unsigned)m;
  }
  __syncthreads();
  const unsigned nCh = nChosen;

  unsigned short out[16];
  #pragma unroll
  for (int j = 0; j < 16; ++j) {
    bool sel = bj[j] > B;
    if (bj[j] == B) {
      unsigned short idx = (unsigned short)(tid * 16 + j);
      for (unsigned q = 0; q < nCh; ++q) if (chosen[q] == idx) { sel = true; break; }
    }
    out[j] = sel ? f2bf(wv[j]) : (unsigned short)0;
  }
  uint4 pk0, pk1;
  pk0.x = out[0] | ((unsigned)out[1]  << 16); pk0.y = out[2]  | ((unsigned)out[3]  << 16);
  pk0.z = out[4] | ((unsigned)out[5]  << 16); pk0.w = out[6]  | ((unsigned)out[7]  << 16);
  pk1.x = out[8] | ((unsigned)out[9]  << 16); pk1.y = out[10] | ((unsigned)out[11] << 16);
  pk1.z = out[12]| ((unsigned)out[13] << 16); pk1.w = out[14] | ((unsigned)out[15] << 16);
  uint4* dst = reinterpret_cast<uint4*>(&g_wb[(size_t)o * INF + tid * 16]);
  dst[0] = pk0; dst[1] = pk1;
}

// ---------------------------------------------------------------------------
// 256x256 8-phase GEMM (m201 template, plain HIP):
//   y[t,o] = sum_k xb[t,k]*wb[o,k] + bias[o]
// 8 waves (2M x 4N), BK=64, 2 K-tiles/iteration, 8 phases each:
//   {ds_read subtile | stage 1 half-tile | (vmcnt@P4/P8) | barrier |
//    lgkmcnt(0)+sched_barrier | setprio(1) 16xMFMA setprio(0) | barrier}
// LDS = 8 x 16KB half-slots (A[4] + B[4]); slot rotation verified:
//   P1:a2<-A(2j+1,h0) P2:a3<-A(2j+1,h1) P3:b0<-B(2j+2,h0) P4:b1<-B(2j+2,h1)
//   P5:a0<-A(2j+2,h0) P6:a1<-A(2j+2,h1) P7:b2<-B(2j+3,h0) P8:b3<-B(2j+3,h1)
// Each stage targets a slot whose last reader finished >=1 barrier earlier;
// vmcnt(4) at P4/P8 retires exactly the halves the next 4 phases read, with
// 2 half-tiles always in flight (never drains to 0 in the main loop).
// st_16x32 swizzle (byte ^= ((byte>>9)&1)<<5): LDS dest linear (required by
// global_load_lds), SOURCE pre-swizzled, ds_read swizzled — same involution.
// ---------------------------------------------------------------------------
typedef __attribute__((ext_vector_type(8))) short bf16x8;
typedef __attribute__((ext_vector_type(4))) float f32x4;

#define LGK0() do { asm volatile("s_waitcnt lgkmcnt(0)" ::: "memory"); \
                    __builtin_amdgcn_sched_barrier(0); } while (0)
#define ENDP() do { __builtin_amdgcn_sched_barrier(0); \
                    __builtin_amdgcn_s_barrier(); } while (0)
#define BARW() __builtin_amdgcn_s_barrier()
#define VMC4() asm volatile("s_waitcnt vmcnt(4)" ::: "memory")
#define VMC0() asm volatile("s_waitcnt vmcnt(0)" ::: "memory")

template <int MQ0>
__device__ __forceinline__ void rdA(bf16x8 aF[4][2], const char* base,
                                    int fr, int c0, int c1) {
  #pragma unroll
  for (int m = 0; m < 4; ++m) {
    aF[m][0] = *reinterpret_cast<const bf16x8*>(base + ((MQ0 + m) * 16 + fr) * 128 + c0);
    aF[m][1] = *reinterpret_cast<const bf16x8*>(base + ((MQ0 + m) * 16 + fr) * 128 + c1);
  }
}
template <int NQ0>
__device__ __forceinline__ void rdB(bf16x8 bF[4][2], const char* base,
                                    int bRow, int fr, int c0, int c1) {
  #pragma unroll
  for (int n = 0; n < 2; ++n) {
    bF[NQ0+n][0] = *reinterpret_cast<const bf16x8*>(base + (bRow + (NQ0+n) * 16 + fr) * 128 + c0);
    bF[NQ0+n][1] = *reinterpret_cast<const bf16x8*>(base + (bRow + (NQ0+n) * 16 + fr) * 128 + c1);
  }
}
template <int MO, int NO>
__device__ __forceinline__ void quad(f32x4 acc[8][4], bf16x8 aF[4][2], bf16x8 bF[4][2]) {
  __builtin_amdgcn_s_setprio(1);
  #pragma unroll
  for (int m = 0; m < 4; ++m)
    #pragma unroll
    for (int n = 0; n < 2; ++n) {
      acc[MO+m][NO+n] = __builtin_amdgcn_mfma_f32_16x16x32_bf16(aF[m][0], bF[NO+n][0], acc[MO+m][NO+n], 0, 0, 0);
      acc[MO+m][NO+n] = __builtin_amdgcn_mfma_f32_16x16x32_bf16(aF[m][1], bF[NO+n][1], acc[MO+m][NO+n], 0, 0, 0);
    }
  __builtin_amdgcn_s_setprio(0);
}

__global__ __launch_bounds__(512, 2) void gemm256(const float* __restrict__ bias,
                                                  float* __restrict__ y) {
  __shared__ char smem[131072];   // A slots [0,64K): 4x16KB; B slots [64K,128K)

  const int tid = threadIdx.x;
  const int wid = tid >> 6, ln = tid & 63;
  const int wr = wid >> 2, wc = wid & 3;           // 2 x 4 waves

  // XCD-aware swizzle (512 blocks, 512 % 8 == 0 -> bijective).
  const int bid = (int)blockIdx.x;
  const int swz = (bid & 7) * 64 + (bid >> 3);
  const int bm = swz >> 4, bn = swz & 15;          // 32 x 16 tiles
  const int m0 = bm * 256, n0 = bn * 256;

  // --- staging constants: physical LDS dest d = wid*1024 + ln*16 (+line*8192)
  // source reads LOGICAL q = d ^ ((d>>9 &1)<<5)  (involution, 16B-preserving)
  const int woff = wid * 1024;
  const int dl   = woff + ln * 16;
  const int q0s  = dl ^ (((dl >> 9) & 1) << 5);
  const int row0 = q0s >> 7;              // 0..63 (line1 -> +64)
  const int kel  = (q0s & 127) >> 1;      // k-element 0..63

  char* const aS0 = smem;                 // A(even) h0
  char* const aS1 = smem + 16384;         // A(even) h1
  char* const aS2 = smem + 32768;         // A(odd)  h0
  char* const aS3 = smem + 49152;         // A(odd)  h1
  char* const bS0 = smem + 65536;
  char* const bS1 = smem + 81920;
  char* const bS2 = smem + 98304;
  char* const bS3 = smem + 114688;

  // --- read-side constants: physical col = logical ^ ((row&4)?32:0); since
  // row = m*16+fr, (row>>2)&1 == (fr>>2)&1  -> per-thread constant.
  const int fr = ln & 15, kq = ln >> 4;
  const int swzb = ((fr >> 2) & 1) << 5;
  const int c0 = (kq * 16) ^ swzb;        // K-window 0 (k 0..31)
  const int c1 = (64 + kq * 16) ^ swzb;   // K-window 1 (k 32..63)
  const char* const aB0 = smem + wr * 16384;            // this wave's A half, even kt
  const char* const aB1 = smem + (2 + wr) * 16384;      // odd kt
  const char* const bB0 = smem + 65536 + (wc >> 1) * 16384;
  const char* const bB1 = smem + 65536 + (2 + (wc >> 1)) * 16384;
  const int bRow = (wc & 1) * 64;

  f32x4 acc[8][4] = {};
  bf16x8 aF[4][2], bF[4][2];

#define STAGE(gbase, rowOrigin, kt, slot) do {                                   \
    const unsigned short* _s0 = (gbase) + (size_t)((rowOrigin) + row0) * 4096    \
                                + (kt) * 64 + kel;                               \
    gload_lds16(_s0, (slot) + woff);                                             \
    gload_lds16(_s0 + (size_t)64 * 4096, (slot) + 8192 + woff);                  \
  } while (0)

  // ---- prologue: A(0)->a0,a1  B(0)->b0,b1  B(1)->b2,b3 ; wait first 4 halves
  STAGE(g_xb, m0,       0, aS0);
  STAGE(g_xb, m0 + 128, 0, aS1);
  STAGE(g_wb, n0,       0, bS0);
  STAGE(g_wb, n0 + 128, 0, bS1);
  STAGE(g_wb, n0,       1, bS2);
  STAGE(g_wb, n0 + 128, 1, bS3);
  VMC4();
  BARW();

  // ---- main loop: j = 0..30 (kt = 2j, 2j+1); all staged kt <= 63 at j=30
  #pragma unroll 1
  for (int j = 0; j < 31; ++j) {
    const int kt = 2 * j;
    // P1: read A m0-3 + B n0-1 (kt even); stage A(kt+1,h0)->a2
    rdA<0>(aF, aB0, fr, c0, c1);
    rdB<0>(bF, bB0, bRow, fr, c0, c1);
    STAGE(g_xb, m0, kt + 1, aS2);
    BARW(); LGK0();
    quad<0, 0>(acc, aF, bF);
    ENDP();
    // P2: read B n2-3; stage A(kt+1,h1)->a3
    rdB<2>(bF, bB0, bRow, fr, c0, c1);
    STAGE(g_xb, m0 + 128, kt + 1, aS3);
    BARW(); LGK0();
    quad<0, 2>(acc, aF, bF);
    ENDP();
    // P3: read A m4-7; stage B(kt+2,h0)->b0
    rdA<4>(aF, aB0, fr, c0, c1);
    STAGE(g_wb, n0, kt + 2, bS0);
    BARW(); LGK0();
    quad<4, 0>(acc, aF, bF);
    ENDP();
    // P4: stage B(kt+2,h1)->b1; counted wait for odd-tile halves
    STAGE(g_wb, n0 + 128, kt + 2, bS1);
    VMC4();
    BARW(); LGK0();
    quad<4, 2>(acc, aF, bF);
    ENDP();
    // P5: read A m0-3 + B n0-1 (kt odd); stage A(kt+2,h0)->a0
    rdA<0>(aF, aB1, fr, c0, c1);
    rdB<0>(bF, bB1, bRow, fr, c0, c1);
    STAGE(g_xb, m0, kt + 2, aS0);
    BARW(); LGK0();
    quad<0, 0>(acc, aF, bF);
    ENDP();
    // P6: read B n2-3; stage A(kt+2,h1)->a1
    rdB<2>(bF, bB1, bRow, fr, c0, c1);
    STAGE(g_xb, m0 + 128, kt + 2, aS1);
    BARW(); LGK0();
    quad<0, 2>(acc, aF, bF);
    ENDP();
    // P7: read A m4-7; stage B(kt+3,h0)->b2
    rdA<4>(aF, aB1, fr, c0, c1);
    STAGE(g_wb, n0, kt + 3, bS2);
    BARW(); LGK0();
    quad<4, 0>(acc, aF, bF);
    ENDP();
    // P8: stage B(kt+3,h1)->b3; counted wait for next even-tile halves
    STAGE(g_wb, n0 + 128, kt + 3, bS3);
    VMC4();
    BARW(); LGK0();
    quad<4, 2>(acc, aF, bF);
    ENDP();
  }

  // ---- epilogue iteration (kt = 62, 63): only A(63) still to stage; drain.
  rdA<0>(aF, aB0, fr, c0, c1);
  rdB<0>(bF, bB0, bRow, fr, c0, c1);
  STAGE(g_xb, m0, 63, aS2);
  BARW(); LGK0();
  quad<0, 0>(acc, aF, bF);
  ENDP();
  rdB<2>(bF, bB0, bRow, fr, c0, c1);
  STAGE(g_xb, m0 + 128, 63, aS3);
  BARW(); LGK0();
  quad<0, 2>(acc, aF, bF);
  ENDP();
  rdA<4>(aF, aB0, fr, c0, c1);
  BARW(); LGK0();
  quad<4, 0>(acc, aF, bF);
  ENDP();
  VMC0();                       // epilogue drain: A(63)/B(63) all landed
  BARW(); LGK0();
  quad<4, 2>(acc, aF, bF);
  ENDP();
  rdA<0>(aF, aB1, fr, c0, c1);
  rdB<0>(bF, bB1, bRow, fr, c0, c1);
  BARW(); LGK0();
  quad<0, 0>(acc, aF, bF);
  ENDP();
  rdB<2>(bF, bB1, bRow, fr, c0, c1);
  BARW(); LGK0();
  quad<0, 2>(acc, aF, bF);
  ENDP();
  rdA<4>(aF, aB1, fr, c0, c1);
  BARW(); LGK0();
  quad<4, 0>(acc, aF, bF);
  ENDP();
  BARW(); LGK0();
  quad<4, 2>(acc, aF, bF);
  __builtin_amdgcn_sched_barrier(0);

  // ---- C-write + bias (C/D layout: col = lane&15, row = (lane>>4)*4 + reg)
  const int fq = ln >> 4;
  #pragma unroll
  for (int n = 0; n < 4; ++n) {
    const int col = n0 + wc * 64 + n * 16 + fr;
    const float bb = bias[col];
    #pragma unroll
    for (int m = 0; m < 8; ++m) {
      const int r = m0 + wr * 128 + m * 16 + fq * 4;
      #pragma unroll
      for (int qq = 0; qq < 4; ++qq)
        y[(size_t)(r + qq) * OUTF + col] = acc[m][n][qq] + bb;
    }
  }
#undef STAGE
}

extern "C" void kernel_launch(void* const* d_in, const int* in_sizes, int n_in,
                              void* d_out, int out_size, void* d_ws, size_t ws_size,
                              hipStream_t stream) {
  const float* x      = (const float*)d_in[0];
  const float* weight = (const float*)d_in[1];
  const float* bias   = (const float*)d_in[2];
  float*       y      = (float*)d_out;

  hipLaunchKernelGGL(xcvt,    dim3(2048), dim3(256), 0, stream, x);
  hipLaunchKernelGGL(topk_wb, dim3(OUTF), dim3(256), 0, stream, weight);
  hipLaunchKernelGGL(gemm256, dim3((NTOK / 256) * (OUTF / 256)), dim3(512), 0, stream,
                     bias, y);
}